// Round 2
// baseline (210.302 us; speedup 1.0000x reference)
//
#include <hip/hip_runtime.h>

#define N_TOK  8192
#define KDIM   4096
#define NE     16
#define NSLICE 4                   // ws partials per token (one per k-quarter block)
#define TB     64                  // tokens per block (= wave width)

// R8: longer per-lane contiguous runs for DRAM page efficiency.
// R7 (direct streaming, 32 strips x 512B/lane) landed partial at ~28us
// (~4.8 TB/s) vs the 21.3us floor; the harness fill proves 6.8 TB/s on this
// chip with full-page linear sweeps. Theory: 512B runs delivered as 8x64B
// requests ~2us apart waste DRAM page activates. Fix: 16 strips x 1KB/lane
// (NSLICE=4, grid 512 = 2 blocks/CU, 8 waves/CU) -> 2x bytes per page
// activate. Prefetch deepened to 8xfloat4 (128B/lane in flight); each pair's
// 512 FMAs (~1024cy/wave) covers the ~900cy HBM latency. Channel-class
// balance preserved: 16 strips x 1KB statically cover the 16KB row period.
// k stays wave-uniform -> gate rows remain free scalar s_loads.
// Prediction: partial ~24us, total 197 -> ~190-193. If <=1us delta: strided
// ceiling reached -> roofline.
__global__ __launch_bounds__(256, 4)
void router_partial(const float* __restrict__ x, const float* __restrict__ gate,
                    float* __restrict__ ws) {
  __shared__ float red[256 * 17];            // cross-wave reduction only
  const int tid  = threadIdx.x;
  const int lane = tid & 63;
  const int w    = __builtin_amdgcn_readfirstlane(tid >> 6);
  const int g    = blockIdx.x >> 2;          // token group (128)
  const int q    = blockIdx.x & 3;           // k-quarter (4) -> ws slice
  const int t0   = g * TB;
  const int sid  = q * 4 + w;                // 16 strips of 256 k
  const int k0   = sid * 256;

  const float4* xr = (const float4*)(x + (size_t)(t0 + lane) * KDIM + k0);
  const float*  gb = gate + (size_t)k0 * NE; // wave-uniform -> scalar s_loads

  float acc[NE];
#pragma unroll
  for (int e = 0; e < NE; ++e) acc[e] = 0.f;

  // 64 float4 loads per lane (1KB contiguous), 2-deep pair ping-pong:
  // 8 pairs x 8 float4 = 128B in flight per lane during each 512-FMA block.
  // All indices compile-time after unroll -> stays in VGPRs (rule-#20 safe).
  float4 cur[8], nxt[8];
#pragma unroll
  for (int u = 0; u < 8; ++u) cur[u] = xr[u];
#pragma unroll
  for (int jp = 0; jp < 8; ++jp) {
    if (jp < 7) {
#pragma unroll
      for (int u = 0; u < 8; ++u) nxt[u] = xr[(jp + 1) * 8 + u];
    }
#pragma unroll
    for (int u = 0; u < 8; ++u) {
      const float xv[4] = {cur[u].x, cur[u].y, cur[u].z, cur[u].w};
#pragma unroll
      for (int m = 0; m < 4; ++m) {
        const float* grow = gb + (size_t)(jp * 32 + u * 4 + m) * NE; // uniform
#pragma unroll
        for (int e = 0; e < NE; ++e) acc[e] = fmaf(xv[m], grow[e], acc[e]);
      }
    }
#pragma unroll
    for (int u = 0; u < 8; ++u) cur[u] = nxt[u];
  }

  // cross-wave reduction (4 strips of 256k -> one 1024k partial), then one
  // float4 per thread into ws[q]
#pragma unroll
  for (int e = 0; e < NE; ++e) red[(w * 64 + lane) * 17 + e] = acc[e];
  __syncthreads();
  {
    int p0 = tid * 4;                        // 1024 (token,e) pairs, 4/thread
    int t  = p0 >> 4, e0 = p0 & 15;
    float v[4];
#pragma unroll
    for (int j = 0; j < 4; ++j) {
      float sum = 0.f;
#pragma unroll
      for (int ww = 0; ww < 4; ++ww) sum += red[(ww * 64 + t) * 17 + e0 + j];
      v[j] = sum;
    }
    *(float4*)(ws + ((size_t)q * N_TOK + (t0 + t)) * NE + e0) =
        make_float4(v[0], v[1], v[2], v[3]);
  }
}

// Sum 4 slice partials, top-2 (earliest-index tie-break = jax top_k),
// sigmoid, scatter into (E,N) scores; token_indices[e][t] = t (as float).
__global__ __launch_bounds__(256)
void router_finalize(const float* __restrict__ ws, float* __restrict__ out) {
  int t = blockIdx.x * 256 + threadIdx.x;
  float l[NE];
#pragma unroll
  for (int e = 0; e < NE; ++e) l[e] = 0.f;
#pragma unroll
  for (int s = 0; s < NSLICE; ++s) {
    const float4* row = (const float4*)(ws + ((size_t)s * N_TOK + t) * NE);
    float4 r0 = row[0], r1 = row[1], r2 = row[2], r3 = row[3];
    l[0]  += r0.x; l[1]  += r0.y; l[2]  += r0.z; l[3]  += r0.w;
    l[4]  += r1.x; l[5]  += r1.y; l[6]  += r1.z; l[7]  += r1.w;
    l[8]  += r2.x; l[9]  += r2.y; l[10] += r2.z; l[11] += r2.w;
    l[12] += r3.x; l[13] += r3.y; l[14] += r3.z; l[15] += r3.w;
  }
  int i1 = 0; float v1 = l[0];
#pragma unroll
  for (int e = 1; e < NE; ++e) { if (l[e] > v1) { v1 = l[e]; i1 = e; } }
  int i2 = -1; float v2 = -1e30f;
#pragma unroll
  for (int e = 0; e < NE; ++e) { if (e != i1 && l[e] > v2) { v2 = l[e]; i2 = e; } }
  float s1 = 1.f / (1.f + __expf(-v1));
  float s2 = 1.f / (1.f + __expf(-v2));
  float* scores = out;
  float* tix    = out + (size_t)NE * N_TOK;
  float tf = (float)t;
#pragma unroll
  for (int e = 0; e < NE; ++e) {             // coalesced across lanes per e
    scores[(size_t)e * N_TOK + t] = (e == i1) ? s1 : ((e == i2) ? s2 : 0.f);
    tix[(size_t)e * N_TOK + t]    = tf;
  }
}

extern "C" void kernel_launch(void* const* d_in, const int* in_sizes, int n_in,
                              void* d_out, int out_size, void* d_ws, size_t ws_size,
                              hipStream_t stream) {
  const float* x    = (const float*)d_in[0];
  const float* gate = (const float*)d_in[1];
  float* out = (float*)d_out;
  float* ws  = (float*)d_ws;   // needs NSLICE*N_TOK*NE*4 = 2 MB
  router_partial<<<dim3(N_TOK / TB * NSLICE), dim3(256), 0, stream>>>(x, gate, ws);
  router_finalize<<<dim3(N_TOK / 256), dim3(256), 0, stream>>>(ws, out);
}

// Round 4
// 200.415 us; speedup vs baseline: 1.0493x; 1.0493x over previous
//
#include <hip/hip_runtime.h>

#define N_TOK  8192
#define KDIM   4096
#define NE     16
#define NSLICE 16                  // ws partials per token (one per k-16th block)
#define TB     64                  // tokens per block (= wave width)

// R10: R9's max-occupancy geometry, de-risked launch bounds.
// R9 aborted at run/build; addressing re-audit found no OOB (x<=4095,
// gate<=65535, ws 8MB << 512MiB workspace, red 4350<4352). Prime suspect:
// __launch_bounds__(256,8) forcing a <=64-VGPR budget. R10 keeps the
// geometry (2048 blocks = 8/CU = 32 waves/CU if VGPR<=64 naturally; 64-k
// strips = 256B/lane runs; cur[2]/nxt[2] prefetch ~52 VGPR) with the proven
// (256,4) bound -- the min-waves arg is only a cap, not the achieved
// occupancy. R8 proved latency/TLP-bound (fewer waves -> +13us); R10 doubles
// waves vs R7. In-flight demand 32w x 64l x 32B = 64KB/CU >> ~9KB
// latency-BW product. k stays wave-uniform -> gate rows are scalar s_loads.
// Prediction: partial ~34 -> 24-27us, total 197 -> ~188-193. Flat => roofline.
__global__ __launch_bounds__(256, 4)
void router_partial(const float* __restrict__ x, const float* __restrict__ gate,
                    float* __restrict__ ws) {
  __shared__ float red[256 * 17];            // cross-wave reduction only
  const int tid  = threadIdx.x;
  const int lane = tid & 63;
  const int w    = __builtin_amdgcn_readfirstlane(tid >> 6);
  const int g    = blockIdx.x >> 4;          // token group (128)
  const int q    = blockIdx.x & 15;          // k-16th (16) -> ws slice
  const int t0   = g * TB;
  const int sid  = q * 4 + w;                // 64 strips of 64 k
  const int k0   = sid * 64;

  const float4* xr = (const float4*)(x + (size_t)(t0 + lane) * KDIM + k0);
  const float*  gb = gate + (size_t)k0 * NE; // wave-uniform -> scalar s_loads

  float acc[NE];
#pragma unroll
  for (int e = 0; e < NE; ++e) acc[e] = 0.f;

  // 16 float4 loads per lane (256B contiguous), 2-deep pair ping-pong:
  // 2 float4 (32B) in flight per lane during each 128-FMA block. All indices
  // compile-time after unroll -> stays in VGPRs (rule-#20 safe).
  float4 cur[2], nxt[2];
#pragma unroll
  for (int u = 0; u < 2; ++u) cur[u] = xr[u];
#pragma unroll
  for (int jc = 0; jc < 8; ++jc) {
    if (jc < 7) {
#pragma unroll
      for (int u = 0; u < 2; ++u) nxt[u] = xr[(jc + 1) * 2 + u];
    }
#pragma unroll
    for (int u = 0; u < 2; ++u) {
      const float xv[4] = {cur[u].x, cur[u].y, cur[u].z, cur[u].w};
#pragma unroll
      for (int m = 0; m < 4; ++m) {
        const float* grow = gb + (size_t)(jc * 8 + u * 4 + m) * NE; // uniform
#pragma unroll
        for (int e = 0; e < NE; ++e) acc[e] = fmaf(xv[m], grow[e], acc[e]);
      }
    }
#pragma unroll
    for (int u = 0; u < 2; ++u) cur[u] = nxt[u];
  }

  // cross-wave reduction (4 strips of 64k -> one 256k partial), then one
  // float4 per thread into ws[q]
#pragma unroll
  for (int e = 0; e < NE; ++e) red[(w * 64 + lane) * 17 + e] = acc[e];
  __syncthreads();
  {
    int p0 = tid * 4;                        // 1024 (token,e) pairs, 4/thread
    int t  = p0 >> 4, e0 = p0 & 15;
    float v[4];
#pragma unroll
    for (int j = 0; j < 4; ++j) {
      float sum = 0.f;
#pragma unroll
      for (int ww = 0; ww < 4; ++ww) sum += red[(ww * 64 + t) * 17 + e0 + j];
      v[j] = sum;
    }
    *(float4*)(ws + ((size_t)q * N_TOK + (t0 + t)) * NE + e0) =
        make_float4(v[0], v[1], v[2], v[3]);
  }
}

// Sum 16 slice partials, top-2 (earliest-index tie-break = jax top_k),
// sigmoid, scatter into (E,N) scores; token_indices[e][t] = t (as float).
__global__ __launch_bounds__(256)
void router_finalize(const float* __restrict__ ws, float* __restrict__ out) {
  int t = blockIdx.x * 256 + threadIdx.x;
  float l[NE];
#pragma unroll
  for (int e = 0; e < NE; ++e) l[e] = 0.f;
#pragma unroll
  for (int s = 0; s < NSLICE; ++s) {
    const float4* row = (const float4*)(ws + ((size_t)s * N_TOK + t) * NE);
    float4 r0 = row[0], r1 = row[1], r2 = row[2], r3 = row[3];
    l[0]  += r0.x; l[1]  += r0.y; l[2]  += r0.z; l[3]  += r0.w;
    l[4]  += r1.x; l[5]  += r1.y; l[6]  += r1.z; l[7]  += r1.w;
    l[8]  += r2.x; l[9]  += r2.y; l[10] += r2.z; l[11] += r2.w;
    l[12] += r3.x; l[13] += r3.y; l[14] += r3.z; l[15] += r3.w;
  }
  int i1 = 0; float v1 = l[0];
#pragma unroll
  for (int e = 1; e < NE; ++e) { if (l[e] > v1) { v1 = l[e]; i1 = e; } }
  int i2 = -1; float v2 = -1e30f;
#pragma unroll
  for (int e = 0; e < NE; ++e) { if (e != i1 && l[e] > v2) { v2 = l[e]; i2 = e; } }
  float s1 = 1.f / (1.f + __expf(-v1));
  float s2 = 1.f / (1.f + __expf(-v2));
  float* scores = out;
  float* tix    = out + (size_t)NE * N_TOK;
  float tf = (float)t;
#pragma unroll
  for (int e = 0; e < NE; ++e) {             // coalesced across lanes per e
    scores[(size_t)e * N_TOK + t] = (e == i1) ? s1 : ((e == i2) ? s2 : 0.f);
    tix[(size_t)e * N_TOK + t]    = tf;
  }
}

extern "C" void kernel_launch(void* const* d_in, const int* in_sizes, int n_in,
                              void* d_out, int out_size, void* d_ws, size_t ws_size,
                              hipStream_t stream) {
  const float* x    = (const float*)d_in[0];
  const float* gate = (const float*)d_in[1];
  float* out = (float*)d_out;
  float* ws  = (float*)d_ws;   // needs NSLICE*N_TOK*NE*4 = 8 MB
  router_partial<<<dim3(N_TOK / TB * NSLICE), dim3(256), 0, stream>>>(x, gate, ws);
  router_finalize<<<dim3(N_TOK / 256), dim3(256), 0, stream>>>(ws, out);
}